// Round 1
// baseline (229.116 us; speedup 1.0000x reference)
//
#include <hip/hip_runtime.h>
#include <math.h>

// Problem constants
#define NB 4
#define TT 256
#define DMODEL 1024
#define NE 16
#define DLQ 64
#define NH 4
#define HD 16
#define SEQL 17
#define NTOK 1024   // NB*TT

// Workspace layout (float offsets)
static constexpr size_t WS_P     = 0;                         // 4 x 1024x1024 GEMM partials (K-split 4)
static constexpr size_t WS_XPART = 4u * 1024u * 1024u;        // 32 x 1024 batch column-sum partials
static constexpr size_t WS_GCTX  = WS_XPART + 32u * 1024u;    // 4 x 64
static constexpr size_t WS_GB    = WS_GCTX + 256u;            // 4 x 16
static constexpr size_t WS_SP    = WS_GB + 64u;               // 16 sum of probs per expert
static constexpr size_t WS_SC    = WS_SP + 16u;               // 16 selection counts per expert

__device__ __forceinline__ float gelu_exact(float x) {
    return 0.5f * x * (1.0f + erff(x * 0.70710678118654752f));
}

// K1a: per-(batch, slice) column sums of x over 32 timesteps; also zero aux accumulators.
__global__ __launch_bounds__(256) void k_batch_partial(const float* __restrict__ x,
                                                       float* __restrict__ ws) {
    int b = blockIdx.x >> 3;
    int g = blockIdx.x & 7;
    int tid = threadIdx.x;
    const float* xp = x + (size_t)b * TT * DMODEL + (size_t)g * 32 * DMODEL + tid * 4;
    float4 acc = {0.f, 0.f, 0.f, 0.f};
#pragma unroll 4
    for (int t = 0; t < 32; ++t) {
        float4 v = *(const float4*)(xp + (size_t)t * DMODEL);
        acc.x += v.x; acc.y += v.y; acc.z += v.z; acc.w += v.w;
    }
    *(float4*)(ws + WS_XPART + (size_t)blockIdx.x * DMODEL + tid * 4) = acc;
    if (blockIdx.x == 0 && tid < 32) ws[WS_SP + tid] = 0.0f;  // SP(16) + SC(16) contiguous
}

// K1b: per batch: xmean -> gctx -> gelu MLP -> gb
__global__ __launch_bounds__(256) void k_global_ctx(const float* __restrict__ gp_w,
                                                    const float* __restrict__ gp_b,
                                                    const float* __restrict__ g1_w,
                                                    const float* __restrict__ g1_b,
                                                    const float* __restrict__ g2_w,
                                                    const float* __restrict__ g2_b,
                                                    float* __restrict__ ws) {
    int b = blockIdx.x, tid = threadIdx.x;
    __shared__ float xm[DMODEL];
    __shared__ float gc[DLQ];
    __shared__ float gb1[128];
    float4 a = {0.f, 0.f, 0.f, 0.f};
#pragma unroll
    for (int g = 0; g < 8; ++g) {
        float4 v = *(const float4*)(ws + WS_XPART + (size_t)(b * 8 + g) * DMODEL + tid * 4);
        a.x += v.x; a.y += v.y; a.z += v.z; a.w += v.w;
    }
    const float inv_t = 1.0f / (float)TT;
    xm[tid * 4 + 0] = a.x * inv_t;
    xm[tid * 4 + 1] = a.y * inv_t;
    xm[tid * 4 + 2] = a.z * inv_t;
    xm[tid * 4 + 3] = a.w * inv_t;
    __syncthreads();
    if (tid < DLQ) {
        const float* wr = gp_w + (size_t)tid * DMODEL;
        float s = 0.f;
        for (int j = 0; j < DMODEL; j += 4) {
            float4 w4 = *(const float4*)(wr + j);
            float4 x4 = *(const float4*)&xm[j];
            s += w4.x * x4.x + w4.y * x4.y + w4.z * x4.z + w4.w * x4.w;
        }
        float v = s + gp_b[tid];
        gc[tid] = v;
        ws[WS_GCTX + b * DLQ + tid] = v;
    }
    __syncthreads();
    if (tid < 128) {
        const float* wr = g1_w + (size_t)tid * DLQ;
        float s = 0.f;
        for (int j = 0; j < DLQ; j += 4) {
            float4 w4 = *(const float4*)(wr + j);
            float4 x4 = *(const float4*)&gc[j];
            s += w4.x * x4.x + w4.y * x4.y + w4.z * x4.z + w4.w * x4.w;
        }
        gb1[tid] = gelu_exact(s + g1_b[tid]);
    }
    __syncthreads();
    if (tid < NE) {
        const float* wr = g2_w + (size_t)tid * 128;
        float s = 0.f;
        for (int j = 0; j < 128; ++j) s += wr[j] * gb1[j];
        ws[WS_GB + b * NE + tid] = s + g2_b[tid];
    }
}

// K2: ef partial GEMM. C[n,m] = sum_k X[n,k] * W[m,k], K-split by blockIdx.z into 4 chunks of 256.
__global__ __launch_bounds__(256) void k_ef_gemm(const float* __restrict__ X,
                                                 const float* __restrict__ W,
                                                 float* __restrict__ ws) {
    __shared__ float As[64][20];  // padded rows: 80B = 5*16B, keeps float4 alignment, 2-way banks
    __shared__ float Bs[64][20];
    int tid = threadIdx.x;
    int m0 = blockIdx.x * 64;
    int n0 = blockIdx.y * 64;
    int kz = blockIdx.z;
    int lr = tid >> 2;
    int lk = (tid & 3) * 4;
    const float* Ap = X + (size_t)(n0 + lr) * DMODEL + kz * 256 + lk;
    const float* Bp = W + (size_t)(m0 + lr) * DMODEL + kz * 256 + lk;
    int ti = tid >> 4;    // 0..3  (row group)
    int tj = tid & 15;    // 0..15 (col group)
    float acc[4][4] = {{0.f}};
    for (int kk = 0; kk < 256; kk += 16) {
        float4 av = *(const float4*)(Ap + kk);
        float4 bv = *(const float4*)(Bp + kk);
        *(float4*)&As[lr][lk] = av;
        *(float4*)&Bs[lr][lk] = bv;
        __syncthreads();
#pragma unroll
        for (int kq = 0; kq < 4; ++kq) {
            float4 a4[4], b4[4];
#pragma unroll
            for (int i = 0; i < 4; ++i) a4[i] = *(const float4*)&As[ti + 16 * i][kq * 4];
#pragma unroll
            for (int j = 0; j < 4; ++j) b4[j] = *(const float4*)&Bs[tj + 16 * j][kq * 4];
#pragma unroll
            for (int i = 0; i < 4; ++i)
#pragma unroll
                for (int j = 0; j < 4; ++j)
                    acc[i][j] += a4[i].x * b4[j].x + a4[i].y * b4[j].y +
                                 a4[i].z * b4[j].z + a4[i].w * b4[j].w;
        }
        __syncthreads();
    }
    float* P = ws + WS_P + (size_t)kz * (NTOK * DMODEL);
#pragma unroll
    for (int i = 0; i < 4; ++i)
#pragma unroll
        for (int j = 0; j < 4; ++j)
            P[(size_t)(n0 + ti + 16 * i) * DMODEL + (m0 + tj + 16 * j)] = acc[i][j];
}

// K3: per-token attention + routing + expert-up mixing. One block (256 threads) per token.
__global__ __launch_bounds__(256) void k_token(const float* __restrict__ pos_embed,
                                               const float* __restrict__ attn_in_w,
                                               const float* __restrict__ attn_in_b,
                                               const float* __restrict__ attn_out_w,
                                               const float* __restrict__ attn_out_b,
                                               const float* __restrict__ ln_w,
                                               const float* __restrict__ ln_b,
                                               const float* __restrict__ ls_w,
                                               const float* __restrict__ ls_b,
                                               const float* __restrict__ w_up,
                                               float* __restrict__ ws,
                                               float* __restrict__ out) {
    int n = blockIdx.x, tid = threadIdx.x;
    int b = n >> 8;  // T=256
    __shared__ float sef[DMODEL];
    __shared__ float seq[SEQL][DLQ];
    __shared__ float qs[SEQL][DLQ], ks2[SEQL][DLQ], vs[SEQL][DLQ];
    __shared__ float att[NH][SEQL][SEQL];
    __shared__ float ctxs[SEQL][DLQ];
    __shared__ float gcs[DLQ], gbs[NE];
    __shared__ float mus[SEQL], rss[SEQL];
    __shared__ float logits[NE], probs[NE];
    __shared__ float tws[2];
    __shared__ int tis[2];
    __shared__ float acts[2][DLQ];

    // ef[n] = sum of 4 K-split partials
    {
        float4 a = {0.f, 0.f, 0.f, 0.f};
#pragma unroll
        for (int z = 0; z < 4; ++z) {
            float4 v = *(const float4*)(ws + WS_P + (size_t)z * (NTOK * DMODEL) +
                                        (size_t)n * DMODEL + tid * 4);
            a.x += v.x; a.y += v.y; a.z += v.z; a.w += v.w;
        }
        *(float4*)&sef[tid * 4] = a;
    }
    if (tid < DLQ) gcs[tid] = ws[WS_GCTX + b * DLQ + tid];
    if (tid < NE) gbs[tid] = ws[WS_GB + b * NE + tid];
    __syncthreads();

    // seq = [gctx ; ef + pos_embed]
    for (int idx = tid; idx < SEQL * DLQ; idx += 256) {
        int i = idx >> 6, j = idx & 63;
        seq[i][j] = (i == 0) ? gcs[j] : sef[(i - 1) * DLQ + j] + pos_embed[(i - 1) * DLQ + j];
    }
    __syncthreads();

    // qkv: column-per-thread, seq broadcast from LDS
    if (tid < 192) {
        int o = tid;
        float a[SEQL];
#pragma unroll
        for (int i = 0; i < SEQL; ++i) a[i] = 0.f;
        const float* wr = attn_in_w + (size_t)o * DLQ;
        for (int j0 = 0; j0 < DLQ; j0 += 4) {
            float4 w4 = *(const float4*)(wr + j0);
#pragma unroll
            for (int i = 0; i < SEQL; ++i) {
                float4 s4 = *(const float4*)&seq[i][j0];
                a[i] += s4.x * w4.x + s4.y * w4.y + s4.z * w4.z + s4.w * w4.w;
            }
        }
        float bo = attn_in_b[o];
        if (o < 64) {
#pragma unroll
            for (int i = 0; i < SEQL; ++i) qs[i][o] = a[i] + bo;
        } else if (o < 128) {
#pragma unroll
            for (int i = 0; i < SEQL; ++i) ks2[i][o - 64] = a[i] + bo;
        } else {
#pragma unroll
            for (int i = 0; i < SEQL; ++i) vs[i][o - 128] = a[i] + bo;
        }
    }
    __syncthreads();

    // scores
    for (int idx = tid; idx < NH * SEQL * SEQL; idx += 256) {
        int h = idx / (SEQL * SEQL);
        int r = idx - h * SEQL * SEQL;
        int i = r / SEQL, kk = r - i * SEQL;
        float s = 0.f;
#pragma unroll
        for (int d = 0; d < HD; ++d) s += qs[i][h * HD + d] * ks2[kk][h * HD + d];
        att[h][i][kk] = s * 0.25f;  // 1/sqrt(16)
    }
    __syncthreads();

    // softmax per (h, i)
    if (tid < NH * SEQL) {
        int h = tid / SEQL, i = tid - h * SEQL;
        float m = -1e30f;
#pragma unroll
        for (int kk = 0; kk < SEQL; ++kk) m = fmaxf(m, att[h][i][kk]);
        float ssum = 0.f;
#pragma unroll
        for (int kk = 0; kk < SEQL; ++kk) {
            float e = expf(att[h][i][kk] - m);
            att[h][i][kk] = e;
            ssum += e;
        }
        float inv = 1.f / ssum;
#pragma unroll
        for (int kk = 0; kk < SEQL; ++kk) att[h][i][kk] *= inv;
    }
    __syncthreads();

    // ctx
    for (int idx = tid; idx < SEQL * DLQ; idx += 256) {
        int i = idx >> 6, c = idx & 63;
        int h = c >> 4;
        float s = 0.f;
#pragma unroll
        for (int kk = 0; kk < SEQL; ++kk) s += att[h][i][kk] * vs[kk][c];
        ctxs[i][c] = s;
    }
    __syncthreads();

    // attn_out + residual (into seq)
    if (tid < DLQ) {
        int o = tid;
        float a[SEQL];
#pragma unroll
        for (int i = 0; i < SEQL; ++i) a[i] = 0.f;
        const float* wr = attn_out_w + (size_t)o * DLQ;
        for (int j0 = 0; j0 < DLQ; j0 += 4) {
            float4 w4 = *(const float4*)(wr + j0);
#pragma unroll
            for (int i = 0; i < SEQL; ++i) {
                float4 c4 = *(const float4*)&ctxs[i][j0];
                a[i] += c4.x * w4.x + c4.y * w4.y + c4.z * w4.z + c4.w * w4.w;
            }
        }
        float bo = attn_out_b[o];
#pragma unroll
        for (int i = 0; i < SEQL; ++i) seq[i][o] += a[i] + bo;
    }
    __syncthreads();

    // LN stats per row
    if (tid < SEQL) {
        float s = 0.f;
#pragma unroll
        for (int j = 0; j < DLQ; ++j) s += seq[tid][j];
        float m = s * (1.0f / DLQ);
        float v = 0.f;
#pragma unroll
        for (int j = 0; j < DLQ; ++j) {
            float d = seq[tid][j] - m;
            v += d * d;
        }
        mus[tid] = m;
        rss[tid] = rsqrtf(v * (1.0f / DLQ) + 1e-5f);
    }
    __syncthreads();

    // local logits (+gb): only rows 1..16 of hn are ever used
    if (tid < NE) {
        int e = tid;
        float m = mus[1 + e], r = rss[1 + e];
        float s = 0.f;
#pragma unroll
        for (int j = 0; j < DLQ; ++j) {
            float hn = (seq[1 + e][j] - m) * r * ln_w[j] + ln_b[j];
            s += hn * ls_w[j];
        }
        logits[e] = s + ls_b[0] + gbs[e];
    }
    __syncthreads();

    // softmax over experts + top-2 (tie -> lower index, matching lax.top_k)
    if (tid == 0) {
        float m = logits[0];
#pragma unroll
        for (int e = 1; e < NE; ++e) m = fmaxf(m, logits[e]);
        float ssum = 0.f;
        float p[NE];
#pragma unroll
        for (int e = 0; e < NE; ++e) {
            p[e] = expf(logits[e] - m);
            ssum += p[e];
        }
        float inv = 1.f / ssum;
#pragma unroll
        for (int e = 0; e < NE; ++e) probs[e] = p[e] * inv;
        int t0 = 0;
        float b0 = probs[0];
#pragma unroll
        for (int e = 1; e < NE; ++e)
            if (probs[e] > b0) { b0 = probs[e]; t0 = e; }
        int t1 = -1;
        float b1 = -1.f;
#pragma unroll
        for (int e = 0; e < NE; ++e)
            if (e != t0 && probs[e] > b1) { b1 = probs[e]; t1 = e; }
        float sw = b0 + b1;
        tis[0] = t0; tis[1] = t1;
        tws[0] = b0 / sw; tws[1] = b1 / sw;
    }
    __syncthreads();

    if (tid < NE) atomicAdd(&ws[WS_SP + tid], probs[tid]);
    if (tid < 2) atomicAdd(&ws[WS_SC + tis[tid]], 1.0f);

    // act = gelu(raw ef of selected experts), pre-scaled by normalized weight
    if (tid < 2 * DLQ) {
        int kk = tid >> 6, j = tid & 63;
        acts[kk][j] = gelu_exact(sef[tis[kk] * DLQ + j]) * tws[kk];
    }
    __syncthreads();

    // out[n, :] = sum_k sum_j acts[k][j] * w_up[e_k][j][:]
    {
        float4 acc = {0.f, 0.f, 0.f, 0.f};
#pragma unroll
        for (int kk = 0; kk < 2; ++kk) {
            const float* wbase = w_up + (size_t)tis[kk] * DLQ * DMODEL + tid * 4;
            for (int j = 0; j < DLQ; ++j) {
                float s = acts[kk][j];
                float4 wv = *(const float4*)(wbase + (size_t)j * DMODEL);
                acc.x += s * wv.x; acc.y += s * wv.y;
                acc.z += s * wv.z; acc.w += s * wv.w;
            }
        }
        *(float4*)(out + (size_t)n * DMODEL + tid * 4) = acc;
    }
}

// K4: aux loss finisher
__global__ void k_aux(const float* __restrict__ ws, float* __restrict__ out) {
    if (threadIdx.x == 0) {
        float s = 0.f;
#pragma unroll
        for (int e = 0; e < NE; ++e) s += ws[WS_SP + e] * ws[WS_SC + e];
        out[(size_t)NTOK * DMODEL] = (float)NE * s / ((float)NTOK * (float)NTOK);
    }
}

extern "C" void kernel_launch(void* const* d_in, const int* in_sizes, int n_in,
                              void* d_out, int out_size, void* d_ws, size_t ws_size,
                              hipStream_t stream) {
    const float* x          = (const float*)d_in[0];
    const float* w_down     = (const float*)d_in[1];
    const float* pos_embed  = (const float*)d_in[2];
    const float* gp_w       = (const float*)d_in[3];
    const float* gp_b       = (const float*)d_in[4];
    const float* attn_in_w  = (const float*)d_in[5];
    const float* attn_in_b  = (const float*)d_in[6];
    const float* attn_out_w = (const float*)d_in[7];
    const float* attn_out_b = (const float*)d_in[8];
    const float* ln_w       = (const float*)d_in[9];
    const float* ln_b       = (const float*)d_in[10];
    const float* ls_w       = (const float*)d_in[11];
    const float* ls_b       = (const float*)d_in[12];
    const float* g1_w       = (const float*)d_in[13];
    const float* g1_b       = (const float*)d_in[14];
    const float* g2_w       = (const float*)d_in[15];
    const float* g2_b       = (const float*)d_in[16];
    const float* w_up       = (const float*)d_in[17];
    float* ws  = (float*)d_ws;
    float* out = (float*)d_out;

    k_batch_partial<<<32, 256, 0, stream>>>(x, ws);
    k_global_ctx<<<NB, 256, 0, stream>>>(gp_w, gp_b, g1_w, g1_b, g2_w, g2_b, ws);
    k_ef_gemm<<<dim3(16, 16, 4), 256, 0, stream>>>(x, w_down, ws);
    k_token<<<NTOK, 256, 0, stream>>>(pos_embed, attn_in_w, attn_in_b, attn_out_w, attn_out_b,
                                      ln_w, ln_b, ls_w, ls_b, w_up, ws, out);
    k_aux<<<1, 64, 0, stream>>>(ws, out);
}